// Round 1
// baseline (2331.633 us; speedup 1.0000x reference)
//
#include <hip/hip_runtime.h>

typedef unsigned short u16;
typedef __attribute__((ext_vector_type(8))) short bf16x8;   // 8 bf16 (4 VGPRs)
typedef __attribute__((ext_vector_type(4))) float f32x4;

#define D_EMB 1024
#define NBAT  256

__device__ __forceinline__ u16 f2bf(float f){
    unsigned int u = __float_as_uint(f);
    unsigned int r = (u + 0x7fffu + ((u >> 16) & 1u)) >> 16;  // RNE
    return (u16)r;
}
__device__ __forceinline__ float bf2f(u16 v){
    return __uint_as_float(((unsigned int)v) << 16);
}
__device__ __forceinline__ float leaky(float x){ return x > 0.f ? x : 0.1f * x; }

// ---------------------------------------------------------------------------
// Pack img_emb(+pool_img as row 36) and cap_emb(+pool_txt as row 40) to bf16.
// imgw: [256][37][1024] bf16, capw: [256][41][1024] bf16
// ---------------------------------------------------------------------------
__global__ void pack_kernel(const float* __restrict__ pool_img, const float* __restrict__ img_emb,
                            const float* __restrict__ pool_txt, const float* __restrict__ cap_emb,
                            u16* __restrict__ imgw, u16* __restrict__ capw){
    int row = blockIdx.x;            // 0..19967
    const float* src; u16* dst;
    if (row < NBAT * 37){
        int e = row / 37, rr = row - e * 37;
        src = (rr < 36) ? (img_emb + ((size_t)e * 36 + rr) * D_EMB) : (pool_img + (size_t)e * D_EMB);
        dst = imgw + (size_t)row * D_EMB;
    } else {
        int r2 = row - NBAT * 37;
        int e = r2 / 41, rr = r2 - e * 41;
        src = (rr < 40) ? (cap_emb + ((size_t)e * 40 + rr) * D_EMB) : (pool_txt + (size_t)e * D_EMB);
        dst = capw + (size_t)r2 * D_EMB;
    }
    int t = threadIdx.x;             // 256 threads, 4 floats each
    float4 v = ((const float4*)src)[t];
    unsigned long long pk = (unsigned long long)f2bf(v.x)
        | ((unsigned long long)f2bf(v.y) << 16)
        | ((unsigned long long)f2bf(v.z) << 32)
        | ((unsigned long long)f2bf(v.w) << 48);
    *(unsigned long long*)(dst + (size_t)t * 4) = pk;
}

// ---------------------------------------------------------------------------
// Pool-vector norms (no eps, per reference)
// ---------------------------------------------------------------------------
__global__ void norm_kernel(const float* __restrict__ pool_img, const float* __restrict__ pool_txt,
                            float* __restrict__ w1i, float* __restrict__ w1t){
    __shared__ float red[256];
    int v = blockIdx.x;              // 0..511
    const float* src = (v < 256) ? (pool_img + (size_t)v * D_EMB)
                                 : (pool_txt + (size_t)(v - 256) * D_EMB);
    int t = threadIdx.x;
    float4 x = ((const float4*)src)[t];
    red[t] = x.x*x.x + x.y*x.y + x.z*x.z + x.w*x.w;
    __syncthreads();
    for (int off = 128; off > 0; off >>= 1){
        if (t < off) red[t] += red[t + off];
        __syncthreads();
    }
    if (t == 0){
        float n = sqrtf(red[0]);
        if (v < 256) w1i[v] = n; else w1t[v - 256] = n;
    }
}

// ---------------------------------------------------------------------------
// Gram matrices in fp32: G[b][r][r'] = <img_r, img_r'>, H[i][l][l'] = <cap_l, cap_l'>
// grid = 512 (2 halves per entity). LDS tile stride 129 -> conflict-free reads.
// ---------------------------------------------------------------------------
__global__ void gram_img_kernel(const float* __restrict__ img_emb, float* __restrict__ G){
    int b = blockIdx.x >> 1, half = blockIdx.x & 1;
    __shared__ float tile[36 * 129];
    int t = threadIdx.x;
    float acc3[3] = {0.f, 0.f, 0.f};
    for (int c = 0; c < 8; ++c){
        for (int idx = t; idx < 36 * 128; idx += 256){
            int rr = idx >> 7, cc = idx & 127;
            tile[rr * 129 + cc] = img_emb[((size_t)b * 36 + rr) * D_EMB + c * 128 + cc];
        }
        __syncthreads();
        for (int j = 0; j < 3; ++j){
            int p = half * 648 + j * 256 + t;
            if (p < 648 * (half + 1)){
                int rr = p / 36, r2 = p - rr * 36;
                const float* ta = tile + rr * 129;
                const float* tb = tile + r2 * 129;
                float s = 0.f;
                for (int k = 0; k < 128; ++k) s += ta[k] * tb[k];
                acc3[j] += s;
            }
        }
        __syncthreads();
    }
    for (int j = 0; j < 3; ++j){
        int p = half * 648 + j * 256 + t;
        if (p < 648 * (half + 1)) G[(size_t)b * 1296 + p] = acc3[j];
    }
}

__global__ void gram_cap_kernel(const float* __restrict__ cap_emb, float* __restrict__ H){
    int b = blockIdx.x >> 1, half = blockIdx.x & 1;
    __shared__ float tile[40 * 129];
    int t = threadIdx.x;
    float acc4[4] = {0.f, 0.f, 0.f, 0.f};
    for (int c = 0; c < 8; ++c){
        for (int idx = t; idx < 40 * 128; idx += 256){
            int rr = idx >> 7, cc = idx & 127;
            tile[rr * 129 + cc] = cap_emb[((size_t)b * 40 + rr) * D_EMB + c * 128 + cc];
        }
        __syncthreads();
        for (int j = 0; j < 4; ++j){
            int p = half * 800 + j * 256 + t;
            if (p < 800 * (half + 1)){
                int ll = p / 40, l2 = p - ll * 40;
                const float* ta = tile + ll * 129;
                const float* tb = tile + l2 * 129;
                float s = 0.f;
                for (int k = 0; k < 128; ++k) s += ta[k] * tb[k];
                acc4[j] += s;
            }
        }
        __syncthreads();
    }
    for (int j = 0; j < 4; ++j){
        int p = half * 800 + j * 256 + t;
        if (p < 800 * (half + 1)) H[(size_t)b * 1600 + p] = acc4[j];
    }
}

// ---------------------------------------------------------------------------
// Fused main kernel. One block = 2 images x 2 captions.
// GEMM: C[74][82] = Arows(2x37) . Brows(2x41)^T via mfma_f32_16x16x32_bf16.
//   A row 36 of each image  = pool_img  -> q[l], base
//   B row 40 of each caption = pool_txt -> p[r]
// Post: wave w handles pair (pb=w>>1, pi=w&1) using Gram-matrix quadratic forms.
// LDS budget 61600 B (staging unioned with post scratch) -> 2 blocks/CU.
// ---------------------------------------------------------------------------
__launch_bounds__(256, 2)
__global__ void fused_kernel(const u16* __restrict__ imgw, const u16* __restrict__ capw,
                             const float* __restrict__ G, const float* __restrict__ H,
                             const float* __restrict__ w1i, const float* __restrict__ w1t,
                             float* __restrict__ out){
    __shared__ __align__(16) char smem[61600];
    u16*   sA    = (u16*)smem;                 // [80][72] bf16 (rows 74..79 zero)
    u16*   sB    = (u16*)(smem + 11520);       // [96][72] bf16 (rows 82..95 zero)
    float* Epost = (float*)smem;               // [4][1480] (overlays staging after GEMM)
    u16*   Vpost = (u16*)(smem + 23680);       // [4][1480] bf16
    float* Call  = (float*)(smem + 35520);     // [74][84]
    float* rnbuf = (float*)(smem + 60384);     // [4][36]
    float* cnbuf = (float*)(smem + 60960);     // [4][40]

    int tid = threadIdx.x;
    int lin = blockIdx.x;
    // panel swizzle: 16 panels of 8 i-tiles x 128 b-tiles (L2 cap reuse)
    int pan = lin >> 10;
    int rem = lin & 1023;
    int b_t = rem >> 3;
    int i_t = (pan << 3) | (rem & 7);
    int b0 = b_t * 2, i0 = i_t * 2;
    const u16* Ag = imgw + (size_t)b0 * 37 * D_EMB;   // 74 contiguous rows
    const u16* Bg = capw + (size_t)i0 * 41 * D_EMB;   // 82 contiguous rows

    // zero LDS pad rows once (never rewritten by staging)
    for (int idx = tid; idx < 20 * 72; idx += 256){
        if (idx < 6 * 72) sA[74 * 72 + idx] = 0;
        else              sB[82 * 72 + (idx - 6 * 72)] = 0;
    }

    int wave = tid >> 6, lane = tid & 63;
    int wm = wave >> 1, wn = wave & 1;     // 2x2 wave grid over 5x6 MFMA tiles
    int nTm = wm ? 2 : 3;                  // m-tiles: {wm, wm+2, wm+4} < 5
    f32x4 acc[3][3];
    for (int aa = 0; aa < 3; ++aa)
        for (int bb = 0; bb < 3; ++bb) acc[aa][bb] = (f32x4){0.f, 0.f, 0.f, 0.f};
    int frow = lane & 15;                  // MFMA A/B: row/col = lane&15
    int kq   = (lane >> 4) * 8;            // k = quad*8 + j

    for (int c = 0; c < 16; ++c){          // K chunks of 64
        int k0 = c * 64;
        for (int idx = tid; idx < 1248; idx += 256){   // 74*8 + 82*8 uint4 copies
            const u16* src; u16* dst;
            if (idx < 592){
                int row = idx >> 3, c8 = idx & 7;
                src = Ag + (size_t)row * D_EMB + k0 + c8 * 8;
                dst = sA + row * 72 + c8 * 8;
            } else {
                int j = idx - 592;
                int row = j >> 3, c8 = j & 7;
                src = Bg + (size_t)row * D_EMB + k0 + c8 * 8;
                dst = sB + row * 72 + c8 * 8;
            }
            *(uint4*)dst = *(const uint4*)src;
        }
        __syncthreads();
        #pragma unroll
        for (int kk = 0; kk < 64; kk += 32){
            bf16x8 af[3], bfr[3];
            #pragma unroll
            for (int ni = 0; ni < 3; ++ni){
                int tn = wn + ni * 2;
                bfr[ni] = *(const bf16x8*)(sB + (tn * 16 + frow) * 72 + kk + kq);
            }
            #pragma unroll
            for (int mi = 0; mi < 3; ++mi){
                if (mi < nTm){
                    int tm = wm + mi * 2;
                    af[mi] = *(const bf16x8*)(sA + (tm * 16 + frow) * 72 + kk + kq);
                }
            }
            #pragma unroll
            for (int mi = 0; mi < 3; ++mi){
                if (mi < nTm){
                    #pragma unroll
                    for (int ni = 0; ni < 3; ++ni){
                        acc[mi][ni] = __builtin_amdgcn_mfma_f32_16x16x32_bf16(
                            af[mi], bfr[ni], acc[mi][ni], 0, 0, 0);
                    }
                }
            }
        }
        __syncthreads();
    }

    // C/D layout (measured m89/m91): col = lane&15, row = (lane>>4)*4 + reg
    #pragma unroll
    for (int mi = 0; mi < 3; ++mi){
        if (mi < nTm){
            int tm = wm + mi * 2;
            #pragma unroll
            for (int ni = 0; ni < 3; ++ni){
                int tn = wn + ni * 2;
                int col = tn * 16 + (lane & 15);
                int rbase = tm * 16 + (lane >> 4) * 4;
                if (col < 82){
                    #pragma unroll
                    for (int g = 0; g < 4; ++g){
                        int rowc = rbase + g;
                        if (rowc < 74) Call[rowc * 84 + col] = acc[mi][ni][g];
                    }
                }
            }
        }
    }
    __syncthreads();

    // ----- post-processing: one wave per (b,i) pair -----
    int pb = wave >> 1, pi = wave & 1;
    int bg = b0 + pb, ig = i0 + pi;
    const float* Sv = Call + (pb * 37) * 84 + pi * 41;  // Sv[r*84+l]; p[r]=Sv[r*84+40]; q[l]=Sv[36*84+l]
    const float* Gb = G + (size_t)bg * 1296;
    const float* Hi = H + (size_t)ig * 1600;
    float* Ew = Epost + wave * 1480;
    u16*   Vw = Vpost + wave * 1480;
    float* rn = rnbuf + wave * 36;
    float* cn = cnbuf + wave * 40;
    float w1_txt = w1t[ig];
    float w1_img = w1i[bg];

    // t2i: l2norm over l per region r, softmax over r per word l
    if (lane < 36){
        float s = 0.f;
        for (int l = 0; l < 40; ++l){ float x = leaky(Sv[lane * 84 + l]); s += x * x; }
        rn[lane] = sqrtf(s) + 1e-8f;
    }
    __syncthreads();
    for (int idx = lane; idx < 1440; idx += 64){
        int rr = idx / 40, ll = idx - rr * 40;
        float x = leaky(Sv[rr * 84 + ll]);
        Ew[rr * 41 + ll] = __expf(9.0f * x / rn[rr]);
    }
    __syncthreads();
    for (int idx = lane; idx < 1440; idx += 64){   // V = G . E
        int rr = idx / 40, ll = idx - rr * 40;
        const float* gr = Gb + rr * 36;
        float s = 0.f;
        for (int r2 = 0; r2 < 36; ++r2) s += gr[r2] * Ew[r2 * 41 + ll];
        Vw[rr * 41 + ll] = f2bf(s);
    }
    __syncthreads();
    float simsum = 0.f;
    if (lane < 40){
        float dd = 0.f, num = 0.f, zz = 0.f;
        for (int rr = 0; rr < 36; ++rr){
            float e = Ew[rr * 41 + lane];
            dd  += e;
            num += e * Sv[rr * 84 + 40];           // p[r]
            zz  += e * bf2f(Vw[rr * 41 + lane]);
        }
        float w12 = num / dd;
        float w2  = sqrtf(fmaxf(zz, 0.f)) / dd;
        simsum = w12 / fmaxf(w1_txt * w2, 1e-8f);
    }
    #pragma unroll
    for (int off = 32; off > 0; off >>= 1) simsum += __shfl_down(simsum, off);
    float t2iv = simsum * (1.f / 40.f);
    __syncthreads();

    // i2t: l2norm over r per word l, softmax over l per region r
    if (lane < 40){
        float s = 0.f;
        for (int rr = 0; rr < 36; ++rr){ float x = leaky(Sv[rr * 84 + lane]); s += x * x; }
        cn[lane] = sqrtf(s) + 1e-8f;
    }
    __syncthreads();
    for (int idx = lane; idx < 1440; idx += 64){
        int ll = idx / 36, rr = idx - ll * 36;
        float x = leaky(Sv[rr * 84 + ll]);
        Ew[ll * 37 + rr] = __expf(9.0f * x / cn[ll]);
    }
    __syncthreads();
    for (int idx = lane; idx < 1440; idx += 64){   // V2 = H . E2
        int ll = idx / 36, rr = idx - ll * 36;
        const float* hr = Hi + ll * 40;
        float s = 0.f;
        for (int l2 = 0; l2 < 40; ++l2) s += hr[l2] * Ew[l2 * 37 + rr];
        Vw[ll * 37 + rr] = f2bf(s);
    }
    __syncthreads();
    float sim2 = 0.f;
    if (lane < 36){
        float dd = 0.f, num = 0.f, zz = 0.f;
        for (int ll = 0; ll < 40; ++ll){
            float e = Ew[ll * 37 + lane];
            dd  += e;
            num += e * Sv[36 * 84 + ll];           // q[l]
            zz  += e * bf2f(Vw[ll * 37 + lane]);
        }
        float w12 = num / dd;
        float w2  = sqrtf(fmaxf(zz, 0.f)) / dd;
        sim2 = w12 / fmaxf(w1_img * w2, 1e-8f);
    }
    #pragma unroll
    for (int off = 32; off > 0; off >>= 1) sim2 += __shfl_down(sim2, off);

    if (lane == 0)
        out[bg * 256 + ig] = t2iv + sim2 * (1.f / 36.f) + Sv[36 * 84 + 40];  // +base
}

// ---------------------------------------------------------------------------
extern "C" void kernel_launch(void* const* d_in, const int* in_sizes, int n_in,
                              void* d_out, int out_size, void* d_ws, size_t ws_size,
                              hipStream_t stream){
    const float* pool_img = (const float*)d_in[0];
    const float* img_emb  = (const float*)d_in[1];
    const float* pool_txt = (const float*)d_in[2];
    const float* cap_emb  = (const float*)d_in[3];
    float* out = (float*)d_out;

    char* ws = (char*)d_ws;                         // needs ~43.9 MB
    size_t o = 0;
    u16* imgw = (u16*)(ws + o);  o += (size_t)256 * 37 * 1024 * 2;   // 19,398,656
    u16* capw = (u16*)(ws + o);  o += (size_t)256 * 41 * 1024 * 2;   // 21,495,808
    float* G  = (float*)(ws + o); o += (size_t)256 * 36 * 36 * 4;    //  1,327,104
    float* H  = (float*)(ws + o); o += (size_t)256 * 40 * 40 * 4;    //  1,638,400
    float* w1i = (float*)(ws + o); o += 1024;
    float* w1t = (float*)(ws + o); o += 1024;

    pack_kernel<<<19968, 256, 0, stream>>>(pool_img, img_emb, pool_txt, cap_emb, imgw, capw);
    norm_kernel<<<512, 256, 0, stream>>>(pool_img, pool_txt, w1i, w1t);
    gram_img_kernel<<<512, 256, 0, stream>>>(img_emb, G);
    gram_cap_kernel<<<512, 256, 0, stream>>>(cap_emb, H);
    fused_kernel<<<16384, 256, 0, stream>>>(imgw, capw, G, H, w1i, w1t, out);
}

// Round 2
// 1072.168 us; speedup vs baseline: 2.1747x; 2.1747x over previous
//
#include <hip/hip_runtime.h>

typedef unsigned short u16;
typedef __attribute__((ext_vector_type(8))) short bf16x8;   // 8 bf16 (4 VGPRs)
typedef __attribute__((ext_vector_type(4))) float f32x4;

#define D_EMB 1024
#define NBAT  256
#define AS1 __attribute__((address_space(1)))
#define AS3 __attribute__((address_space(3)))

__device__ __forceinline__ u16 f2bf(float f){
    unsigned int u = __float_as_uint(f);
    unsigned int r = (u + 0x7fffu + ((u >> 16) & 1u)) >> 16;  // RNE
    return (u16)r;
}
__device__ __forceinline__ float leaky(float x){ return x > 0.f ? x : 0.1f * x; }

// ---------------------------------------------------------------------------
// Pack img_emb(+pool_img as row 36) and cap_emb(+pool_txt as row 40) to bf16.
// imgw: [256][37][1024] bf16, capw: [256][41][1024] bf16
// ---------------------------------------------------------------------------
__global__ void pack_kernel(const float* __restrict__ pool_img, const float* __restrict__ img_emb,
                            const float* __restrict__ pool_txt, const float* __restrict__ cap_emb,
                            u16* __restrict__ imgw, u16* __restrict__ capw){
    int row = blockIdx.x;            // 0..19967
    const float* src; u16* dst;
    if (row < NBAT * 37){
        int e = row / 37, rr = row - e * 37;
        src = (rr < 36) ? (img_emb + ((size_t)e * 36 + rr) * D_EMB) : (pool_img + (size_t)e * D_EMB);
        dst = imgw + (size_t)row * D_EMB;
    } else {
        int r2 = row - NBAT * 37;
        int e = r2 / 41, rr = r2 - e * 41;
        src = (rr < 40) ? (cap_emb + ((size_t)e * 40 + rr) * D_EMB) : (pool_txt + (size_t)e * D_EMB);
        dst = capw + (size_t)r2 * D_EMB;
    }
    int t = threadIdx.x;             // 256 threads, 4 floats each
    float4 v = ((const float4*)src)[t];
    unsigned long long pk = (unsigned long long)f2bf(v.x)
        | ((unsigned long long)f2bf(v.y) << 16)
        | ((unsigned long long)f2bf(v.z) << 32)
        | ((unsigned long long)f2bf(v.w) << 48);
    *(unsigned long long*)(dst + (size_t)t * 4) = pk;
}

// ---------------------------------------------------------------------------
// Pool-vector norms
// ---------------------------------------------------------------------------
__global__ void norm_kernel(const float* __restrict__ pool_img, const float* __restrict__ pool_txt,
                            float* __restrict__ w1i, float* __restrict__ w1t){
    __shared__ float red[256];
    int v = blockIdx.x;              // 0..511
    const float* src = (v < 256) ? (pool_img + (size_t)v * D_EMB)
                                 : (pool_txt + (size_t)(v - 256) * D_EMB);
    int t = threadIdx.x;
    float4 x = ((const float4*)src)[t];
    red[t] = x.x*x.x + x.y*x.y + x.z*x.z + x.w*x.w;
    __syncthreads();
    for (int off = 128; off > 0; off >>= 1){
        if (t < off) red[t] += red[t + off];
        __syncthreads();
    }
    if (t == 0){
        float n = sqrtf(red[0]);
        if (v < 256) w1i[v] = n; else w1t[v - 256] = n;
    }
}

// ---------------------------------------------------------------------------
// Gram matrices in fp32: G[b][r][r'] = <img_r, img_r'>, H[i][l][l'] = <cap_l, cap_l'>
// ---------------------------------------------------------------------------
__global__ void gram_img_kernel(const float* __restrict__ img_emb, float* __restrict__ G){
    int b = blockIdx.x >> 1, half = blockIdx.x & 1;
    __shared__ float tile[36 * 129];
    int t = threadIdx.x;
    float acc3[3] = {0.f, 0.f, 0.f};
    for (int c = 0; c < 8; ++c){
        for (int idx = t; idx < 36 * 128; idx += 256){
            int rr = idx >> 7, cc = idx & 127;
            tile[rr * 129 + cc] = img_emb[((size_t)b * 36 + rr) * D_EMB + c * 128 + cc];
        }
        __syncthreads();
        for (int j = 0; j < 3; ++j){
            int p = half * 648 + j * 256 + t;
            if (p < 648 * (half + 1)){
                int rr = p / 36, r2 = p - rr * 36;
                const float* ta = tile + rr * 129;
                const float* tb = tile + r2 * 129;
                float s = 0.f;
                for (int k = 0; k < 128; ++k) s += ta[k] * tb[k];
                acc3[j] += s;
            }
        }
        __syncthreads();
    }
    for (int j = 0; j < 3; ++j){
        int p = half * 648 + j * 256 + t;
        if (p < 648 * (half + 1)) G[(size_t)b * 1296 + p] = acc3[j];
    }
}

__global__ void gram_cap_kernel(const float* __restrict__ cap_emb, float* __restrict__ H){
    int b = blockIdx.x >> 1, half = blockIdx.x & 1;
    __shared__ float tile[40 * 129];
    int t = threadIdx.x;
    float acc4[4] = {0.f, 0.f, 0.f, 0.f};
    for (int c = 0; c < 8; ++c){
        for (int idx = t; idx < 40 * 128; idx += 256){
            int rr = idx >> 7, cc = idx & 127;
            tile[rr * 129 + cc] = cap_emb[((size_t)b * 40 + rr) * D_EMB + c * 128 + cc];
        }
        __syncthreads();
        for (int j = 0; j < 4; ++j){
            int p = half * 800 + j * 256 + t;
            if (p < 800 * (half + 1)){
                int ll = p / 40, l2 = p - ll * 40;
                const float* ta = tile + ll * 129;
                const float* tb = tile + l2 * 129;
                float s = 0.f;
                for (int k = 0; k < 128; ++k) s += ta[k] * tb[k];
                acc4[j] += s;
            }
        }
        __syncthreads();
    }
    for (int j = 0; j < 4; ++j){
        int p = half * 800 + j * 256 + t;
        if (p < 800 * (half + 1)) H[(size_t)b * 1600 + p] = acc4[j];
    }
}

// ---------------------------------------------------------------------------
// Fused main kernel. One block = 2 images x 2 captions.
// Staging: frag-order LDS layout [kk][tile][quad][frow][8 bf16] via
// global_load_lds width=16 -> every frag read is 1024 contiguous bytes
// (conflict-free ds_read_b128). Post: register-resident softmax weights +
// symmetric Gram quadratic forms with wave-uniform (s_load) G/H access.
// LDS: staging 22528 B overlaid by Call (74x85 f32) + rn/cn = 26376 B.
// ---------------------------------------------------------------------------
__launch_bounds__(256, 4)
__global__ void fused_kernel(const u16* __restrict__ imgw, const u16* __restrict__ capw,
                             const float* __restrict__ G, const float* __restrict__ H,
                             const float* __restrict__ w1i, const float* __restrict__ w1t,
                             float* __restrict__ out){
    __shared__ __align__(16) char smem[26624];
    float* Call = (float*)smem;                 // overlay after GEMM: [74][85]
    float* rnb  = (float*)(smem + 25160);       // [4][36]
    float* cnb  = (float*)(smem + 25736);       // [4][40]

    int tid  = threadIdx.x;
    int lane = tid & 63;
    int wave = __builtin_amdgcn_readfirstlane(tid >> 6);
    int frow = lane & 15, q = lane >> 4;

    int lin = blockIdx.x;
    int pan = lin >> 10;                 // panel swizzle for L2 reuse
    int rem = lin & 1023;
    int b_t = rem >> 3;
    int i_t = (pan << 3) | (rem & 7);
    int b0 = b_t * 2, i0 = i_t * 2;
    const u16* Ag = imgw + (size_t)b0 * 37 * D_EMB;   // 74 rows
    const u16* Bg = capw + (size_t)i0 * 41 * D_EMB;   // 82 rows

    // zero the whole staging region once (pad slots stay zero forever)
    {
        uint4 z = {0u,0u,0u,0u};
        for (int off = tid * 16; off < 22528; off += 4096) *(uint4*)(smem + off) = z;
    }

    // ---- staging group setup: 22 groups of 64 x 16B chunks, wave-cyclic ----
    // A groups g in [0,10): tm=g%5, kk=g/5, LDS byte off g*1024
    // B groups g in [10,22): gb=g-10, tn=gb%6, kk=gb/6, off 10240+gb*1024
    const u16* gsrc[6]; int goff[6]; bool gval[6];
    #pragma unroll
    for (int j = 0; j < 6; ++j){
        int g = wave + j * 4;
        gval[j] = false; gsrc[j] = Ag; goff[j] = 0;
        if (g < 22){
            if (g < 10){
                int tm = g % 5, kk = g / 5;
                int row = tm * 16 + frow;
                gsrc[j] = Ag + (size_t)row * D_EMB + kk * 32 + q * 8;
                goff[j] = g * 1024;
                gval[j] = (row < 74);
            } else {
                int gb = g - 10;
                int tn = gb % 6, kk = gb / 6;
                int row = tn * 16 + frow;
                gsrc[j] = Bg + (size_t)row * D_EMB + kk * 32 + q * 8;
                goff[j] = 10240 + gb * 1024;
                gval[j] = (row < 82);
            }
        }
    }

    int wm = wave >> 1, wn = wave & 1;     // 2x2 wave grid over 5x6 MFMA tiles
    int nTm = wm ? 2 : 3;                  // m-tiles {wm, wm+2, wm+4} < 5
    f32x4 acc[3][3];
    #pragma unroll
    for (int aa = 0; aa < 3; ++aa)
        #pragma unroll
        for (int bb = 0; bb < 3; ++bb) acc[aa][bb] = (f32x4){0.f, 0.f, 0.f, 0.f};

    for (int c = 0; c < 16; ++c){          // K chunks of 64
        __syncthreads();                   // prev chunk's frag reads done
        #pragma unroll
        for (int j = 0; j < 6; ++j){
            if (gval[j]){
                __builtin_amdgcn_global_load_lds(
                    (const AS1 void*)(const void*)(gsrc[j] + c * 64),
                    (AS3 void*)(void*)(smem + goff[j] + lane * 16),
                    16, 0, 0);
            }
        }
        __syncthreads();                   // drains vmcnt -> data in LDS
        #pragma unroll
        for (int kk = 0; kk < 2; ++kk){
            bf16x8 bfr[3];
            #pragma unroll
            for (int ni = 0; ni < 3; ++ni){
                int tn = wn + ni * 2;
                bfr[ni] = *(const bf16x8*)(smem + 10240 + ((kk * 6 + tn) * 64 + lane) * 16);
            }
            #pragma unroll
            for (int mi = 0; mi < 3; ++mi){
                if (mi < nTm){
                    int tm = wm + mi * 2;
                    bf16x8 af = *(const bf16x8*)(smem + ((kk * 5 + tm) * 64 + lane) * 16);
                    #pragma unroll
                    for (int ni = 0; ni < 3; ++ni){
                        acc[mi][ni] = __builtin_amdgcn_mfma_f32_16x16x32_bf16(
                            af, bfr[ni], acc[mi][ni], 0, 0, 0);
                    }
                }
            }
        }
    }
    __syncthreads();                       // all frag reads done before overlay

    // C/D layout: col = lane&15 (B-row), row = (lane>>4)*4 + reg (A-row)
    #pragma unroll
    for (int mi = 0; mi < 3; ++mi){
        if (mi < nTm){
            int tm = wm + mi * 2;
            #pragma unroll
            for (int ni = 0; ni < 3; ++ni){
                int tn = wn + ni * 2;
                int col = tn * 16 + frow;
                int rbase = tm * 16 + q * 4;
                if (col < 82){
                    #pragma unroll
                    for (int g = 0; g < 4; ++g){
                        int rowc = rbase + g;
                        if (rowc < 74) Call[rowc * 85 + col] = acc[mi][ni][g];
                    }
                }
            }
        }
    }
    __syncthreads();

    // ----- post-processing: one wave per (b,i) pair, weights in registers -----
    int pb = wave >> 1, pi = wave & 1;
    int bg = b0 + pb, ig = i0 + pi;
    const float* Sv = Call + (pb * 37) * 85 + pi * 41;  // S[r*85+l]; p[r]=S[r*85+40]; qv[l]=S[36*85+l]
    const float* Gb = G + (size_t)bg * 1296;
    const float* Hi = H + (size_t)ig * 1600;
    float w1_txt = w1t[ig];
    float w1_img = w1i[bg];

    // ---- t2i ----
    {   // row norms over words (lanes = regions)
        int r0 = (lane < 36) ? lane : 35;
        float s = 0.f;
        #pragma unroll
        for (int l = 0; l < 40; ++l){ float x = leaky(Sv[r0 * 85 + l]); s = fmaf(x, x, s); }
        if (lane < 36) rnb[wave * 36 + lane] = 1.f / (sqrtf(s) + 1e-8f);
    }
    float t2i_sum;
    {   // lanes = words
        int lc = (lane < 40) ? lane : 39;
        float u[36], dd = 0.f, num = 0.f;
        #pragma unroll
        for (int r = 0; r < 36; ++r){
            float x = leaky(Sv[r * 85 + lc]);
            float e = __expf(9.0f * x * rnb[wave * 36 + r]);
            u[r] = e; dd += e;
            num = fmaf(e, Sv[r * 85 + 40], num);
        }
        float zz = 0.f;
        #pragma unroll
        for (int rr = 0; rr < 36; ++rr){
            float t = 0.f;
            #pragma unroll
            for (int r2 = rr + 1; r2 < 36; ++r2) t = fmaf(Gb[rr * 36 + r2], u[r2], t);
            zz += (2.f * t + Gb[rr * 36 + rr] * u[rr]) * u[rr];
        }
        float w2s = sqrtf(fmaxf(zz, 0.f));
        float sim = (num / dd) / fmaxf(w1_txt * w2s / dd, 1e-8f);
        sim = (lane < 40) ? sim : 0.f;
        #pragma unroll
        for (int off = 32; off > 0; off >>= 1) sim += __shfl_down(sim, off);
        t2i_sum = sim;
    }

    // ---- i2t ----
    {   // column norms over regions (lanes = words)
        int l0 = (lane < 40) ? lane : 39;
        float s = 0.f;
        #pragma unroll
        for (int r = 0; r < 36; ++r){ float x = leaky(Sv[r * 85 + l0]); s = fmaf(x, x, s); }
        if (lane < 40) cnb[wave * 40 + lane] = 1.f / (sqrtf(s) + 1e-8f);
    }
    float i2t_sum;
    {   // lanes = regions
        int rc = (lane < 36) ? lane : 35;
        float v[40], dd = 0.f, num = 0.f;
        #pragma unroll
        for (int l = 0; l < 40; ++l){
            float x = leaky(Sv[rc * 85 + l]);
            float e = __expf(9.0f * x * cnb[wave * 40 + l]);
            v[l] = e; dd += e;
            num = fmaf(e, Sv[36 * 85 + l], num);
        }
        float zz = 0.f;
        #pragma unroll
        for (int ll = 0; ll < 40; ++ll){
            float t = 0.f;
            #pragma unroll
            for (int l2 = ll + 1; l2 < 40; ++l2) t = fmaf(Hi[ll * 40 + l2], v[l2], t);
            zz += (2.f * t + Hi[ll * 40 + ll] * v[ll]) * v[ll];
        }
        float w2s = sqrtf(fmaxf(zz, 0.f));
        float sim = (num / dd) / fmaxf(w1_img * w2s / dd, 1e-8f);
        sim = (lane < 36) ? sim : 0.f;
        #pragma unroll
        for (int off = 32; off > 0; off >>= 1) sim += __shfl_down(sim, off);
        i2t_sum = sim;
    }

    if (lane == 0)
        out[bg * 256 + ig] = t2i_sum * (1.f / 40.f) + i2t_sum * (1.f / 36.f) + Sv[36 * 85 + 40];
}

// ---------------------------------------------------------------------------
extern "C" void kernel_launch(void* const* d_in, const int* in_sizes, int n_in,
                              void* d_out, int out_size, void* d_ws, size_t ws_size,
                              hipStream_t stream){
    const float* pool_img = (const float*)d_in[0];
    const float* img_emb  = (const float*)d_in[1];
    const float* pool_txt = (const float*)d_in[2];
    const float* cap_emb  = (const float*)d_in[3];
    float* out = (float*)d_out;

    char* ws = (char*)d_ws;                         // needs ~43.9 MB
    size_t o = 0;
    u16* imgw = (u16*)(ws + o);  o += (size_t)256 * 37 * 1024 * 2;
    u16* capw = (u16*)(ws + o);  o += (size_t)256 * 41 * 1024 * 2;
    float* G  = (float*)(ws + o); o += (size_t)256 * 36 * 36 * 4;
    float* H  = (float*)(ws + o); o += (size_t)256 * 40 * 40 * 4;
    float* w1i = (float*)(ws + o); o += 1024;
    float* w1t = (float*)(ws + o); o += 1024;

    pack_kernel<<<19968, 256, 0, stream>>>(pool_img, img_emb, pool_txt, cap_emb, imgw, capw);
    norm_kernel<<<512, 256, 0, stream>>>(pool_img, pool_txt, w1i, w1t);
    gram_img_kernel<<<512, 256, 0, stream>>>(img_emb, G);
    gram_cap_kernel<<<512, 256, 0, stream>>>(cap_emb, H);
    fused_kernel<<<16384, 256, 0, stream>>>(imgw, capw, G, H, w1i, w1t, out);
}

// Round 3
// 810.679 us; speedup vs baseline: 2.8761x; 1.3226x over previous
//
#include <hip/hip_runtime.h>

typedef unsigned short u16;
typedef __attribute__((ext_vector_type(8))) short bf16x8;   // 8 bf16 (4 VGPRs)
typedef __attribute__((ext_vector_type(4))) float f32x4;

#define D_EMB 1024
#define NBAT  256
#define AS1 __attribute__((address_space(1)))
#define AS3 __attribute__((address_space(3)))

__device__ __forceinline__ u16 f2bf(float f){
    unsigned int u = __float_as_uint(f);
    unsigned int r = (u + 0x7fffu + ((u >> 16) & 1u)) >> 16;  // RNE
    return (u16)r;
}
__device__ __forceinline__ float leaky(float x){ return x > 0.f ? x : 0.1f * x; }

// ---------------------------------------------------------------------------
// Pack img_emb(+pool_img as row 36) and cap_emb(+pool_txt as row 40) to bf16.
// imgw: [256][37][1024] bf16, capw: [256][41][1024] bf16
// ---------------------------------------------------------------------------
__global__ void pack_kernel(const float* __restrict__ pool_img, const float* __restrict__ img_emb,
                            const float* __restrict__ pool_txt, const float* __restrict__ cap_emb,
                            u16* __restrict__ imgw, u16* __restrict__ capw){
    int row = blockIdx.x;            // 0..19967
    const float* src; u16* dst;
    if (row < NBAT * 37){
        int e = row / 37, rr = row - e * 37;
        src = (rr < 36) ? (img_emb + ((size_t)e * 36 + rr) * D_EMB) : (pool_img + (size_t)e * D_EMB);
        dst = imgw + (size_t)row * D_EMB;
    } else {
        int r2 = row - NBAT * 37;
        int e = r2 / 41, rr = r2 - e * 41;
        src = (rr < 40) ? (cap_emb + ((size_t)e * 40 + rr) * D_EMB) : (pool_txt + (size_t)e * D_EMB);
        dst = capw + (size_t)r2 * D_EMB;
    }
    int t = threadIdx.x;             // 256 threads, 4 floats each
    float4 v = ((const float4*)src)[t];
    unsigned long long pk = (unsigned long long)f2bf(v.x)
        | ((unsigned long long)f2bf(v.y) << 16)
        | ((unsigned long long)f2bf(v.z) << 32)
        | ((unsigned long long)f2bf(v.w) << 48);
    *(unsigned long long*)(dst + (size_t)t * 4) = pk;
}

// ---------------------------------------------------------------------------
// Pool-vector norms
// ---------------------------------------------------------------------------
__global__ void norm_kernel(const float* __restrict__ pool_img, const float* __restrict__ pool_txt,
                            float* __restrict__ w1i, float* __restrict__ w1t){
    __shared__ float red[256];
    int v = blockIdx.x;              // 0..511
    const float* src = (v < 256) ? (pool_img + (size_t)v * D_EMB)
                                 : (pool_txt + (size_t)(v - 256) * D_EMB);
    int t = threadIdx.x;
    float4 x = ((const float4*)src)[t];
    red[t] = x.x*x.x + x.y*x.y + x.z*x.z + x.w*x.w;
    __syncthreads();
    for (int off = 128; off > 0; off >>= 1){
        if (t < off) red[t] += red[t + off];
        __syncthreads();
    }
    if (t == 0){
        float n = sqrtf(red[0]);
        if (v < 256) w1i[v] = n; else w1t[v - 256] = n;
    }
}

// ---------------------------------------------------------------------------
// MFMA Gram kernel (reads packed bf16): blk<256 -> G[b]=E_img E_img^T (R=36),
// else H[b]=E_cap E_cap^T (R=40). Frag-order staging via global_load_lds;
// A-frag == B-frag layout for 16x16x32, so one staged copy serves both sides.
// ---------------------------------------------------------------------------
__launch_bounds__(256, 2)
__global__ void gram_kernel(const u16* __restrict__ imgw, const u16* __restrict__ capw,
                            float* __restrict__ G, float* __restrict__ H){
    __shared__ __align__(16) char gsm[6144];    // 3 tiles x 2 kk x 64 lanes x 16B
    int blk = blockIdx.x;
    int tid = threadIdx.x, lane = tid & 63;
    int wave = __builtin_amdgcn_readfirstlane(tid >> 6);
    int frow = lane & 15, q = lane >> 4;

    const u16* E; float* Gout; int R;
    if (blk < NBAT){ E = imgw + (size_t)blk * 37 * D_EMB; Gout = G + (size_t)blk * 1296; R = 36; }
    else { int b = blk - NBAT; E = capw + (size_t)b * 41 * D_EMB; Gout = H + (size_t)b * 1600; R = 40; }

    {   // zero staging once (pad rows stay zero)
        uint4 z = {0u,0u,0u,0u};
        for (int off = tid * 16; off < 6144; off += 4096) *(uint4*)(gsm + off) = z;
    }

    // staging groups g in [0,6): t=g%3, kk=g/3; slot index = kk*3+t == g? no:
    // keep read addressing (kk*3+t), so define g = kk*3+t directly.
    const u16* gsrc[2]; int goff[2]; bool gval[2];
    #pragma unroll
    for (int j = 0; j < 2; ++j){
        int g = wave + j * 4;
        gval[j] = false; gsrc[j] = E; goff[j] = 0;
        if (g < 6){
            int kk = g / 3, t = g - kk * 3;
            int row = t * 16 + frow;
            gsrc[j] = E + (size_t)row * D_EMB + kk * 32 + q * 8;
            goff[j] = g * 1024;
            gval[j] = (row < R);
        }
    }

    int wm = wave >> 1, wn = wave & 1;   // tm in {wm, wm+2} (trimmed to <3), tn likewise
    int nTm = wm ? 1 : 2, nTn = wn ? 1 : 2;
    f32x4 acc[2][2];
    #pragma unroll
    for (int a = 0; a < 2; ++a)
        #pragma unroll
        for (int b = 0; b < 2; ++b) acc[a][b] = (f32x4){0.f,0.f,0.f,0.f};

    for (int c = 0; c < 16; ++c){
        __syncthreads();
        #pragma unroll
        for (int j = 0; j < 2; ++j){
            if (gval[j]){
                __builtin_amdgcn_global_load_lds(
                    (const AS1 void*)(const void*)(gsrc[j] + c * 64),
                    (AS3 void*)(void*)(gsm + goff[j] + lane * 16),
                    16, 0, 0);
            }
        }
        __syncthreads();
        #pragma unroll
        for (int kk = 0; kk < 2; ++kk){
            bf16x8 fA[2], fB[2];
            #pragma unroll
            for (int mi = 0; mi < 2; ++mi)
                if (mi < nTm) fA[mi] = *(const bf16x8*)(gsm + ((kk * 3 + (wm + mi * 2)) * 64 + lane) * 16);
            #pragma unroll
            for (int ni = 0; ni < 2; ++ni)
                if (ni < nTn) fB[ni] = *(const bf16x8*)(gsm + ((kk * 3 + (wn + ni * 2)) * 64 + lane) * 16);
            #pragma unroll
            for (int mi = 0; mi < 2; ++mi)
                if (mi < nTm)
                    #pragma unroll
                    for (int ni = 0; ni < 2; ++ni)
                        if (ni < nTn)
                            acc[mi][ni] = __builtin_amdgcn_mfma_f32_16x16x32_bf16(
                                fA[mi], fB[ni], acc[mi][ni], 0, 0, 0);
        }
    }

    // epilogue: C row = tm*16 + q*4+g (A-side), col = tn*16 + frow (B-side)
    #pragma unroll
    for (int mi = 0; mi < 2; ++mi){
        if (mi < nTm){
            int tm = wm + mi * 2;
            #pragma unroll
            for (int ni = 0; ni < 2; ++ni){
                if (ni < nTn){
                    int tn = wn + ni * 2;
                    int col = tn * 16 + frow;
                    if (col < R){
                        #pragma unroll
                        for (int g = 0; g < 4; ++g){
                            int row = tm * 16 + q * 4 + g;
                            if (row < R) Gout[row * R + col] = acc[mi][ni][g];
                        }
                    }
                }
            }
        }
    }
}

// ---------------------------------------------------------------------------
// Fused main kernel. One block = 2 images x 2 captions. (See R2 notes.)
// LDS 26624 B; __launch_bounds__(256,6): 6 blocks/CU (6*26624 = 159744 <= 160K).
// ---------------------------------------------------------------------------
__launch_bounds__(256, 6)
__global__ void fused_kernel(const u16* __restrict__ imgw, const u16* __restrict__ capw,
                             const float* __restrict__ G, const float* __restrict__ H,
                             const float* __restrict__ w1i, const float* __restrict__ w1t,
                             float* __restrict__ out){
    __shared__ __align__(16) char smem[26624];
    float* Call = (float*)smem;                 // overlay after GEMM: [74][85]
    float* rnb  = (float*)(smem + 25160);       // [4][36]
    float* cnb  = (float*)(smem + 25736);       // [4][40]

    int tid  = threadIdx.x;
    int lane = tid & 63;
    int wave = __builtin_amdgcn_readfirstlane(tid >> 6);
    int frow = lane & 15, q = lane >> 4;

    int lin = blockIdx.x;
    int pan = lin >> 10;                 // panel swizzle for L2 reuse
    int rem = lin & 1023;
    int b_t = rem >> 3;
    int i_t = (pan << 3) | (rem & 7);
    int b0 = b_t * 2, i0 = i_t * 2;
    const u16* Ag = imgw + (size_t)b0 * 37 * D_EMB;   // 74 rows
    const u16* Bg = capw + (size_t)i0 * 41 * D_EMB;   // 82 rows

    {   // zero staging region once (pad slots stay zero forever)
        uint4 z = {0u,0u,0u,0u};
        for (int off = tid * 16; off < 22528; off += 4096) *(uint4*)(smem + off) = z;
    }

    // staging groups: A g in [0,10): tm=g%5, kk=g/5, off g*1024
    //                 B g in [10,22): gb=g-10, tn=gb%6, kk=gb/6, off 10240+gb*1024
    const u16* gsrc[6]; int goff[6]; bool gval[6];
    #pragma unroll
    for (int j = 0; j < 6; ++j){
        int g = wave + j * 4;
        gval[j] = false; gsrc[j] = Ag; goff[j] = 0;
        if (g < 22){
            if (g < 10){
                int tm = g % 5, kk = g / 5;
                int row = tm * 16 + frow;
                gsrc[j] = Ag + (size_t)row * D_EMB + kk * 32 + q * 8;
                goff[j] = g * 1024;
                gval[j] = (row < 74);
            } else {
                int gb = g - 10;
                int tn = gb % 6, kk = gb / 6;
                int row = tn * 16 + frow;
                gsrc[j] = Bg + (size_t)row * D_EMB + kk * 32 + q * 8;
                goff[j] = 10240 + gb * 1024;
                gval[j] = (row < 82);
            }
        }
    }

    int wm = wave >> 1, wn = wave & 1;     // 2x2 wave grid over 5x6 MFMA tiles
    int nTm = wm ? 2 : 3;                  // m-tiles {wm, wm+2, wm+4} < 5
    f32x4 acc[3][3];
    #pragma unroll
    for (int aa = 0; aa < 3; ++aa)
        #pragma unroll
        for (int bb = 0; bb < 3; ++bb) acc[aa][bb] = (f32x4){0.f, 0.f, 0.f, 0.f};

    for (int c = 0; c < 16; ++c){          // K chunks of 64
        __syncthreads();                   // prev chunk's frag reads done
        #pragma unroll
        for (int j = 0; j < 6; ++j){
            if (gval[j]){
                __builtin_amdgcn_global_load_lds(
                    (const AS1 void*)(const void*)(gsrc[j] + c * 64),
                    (AS3 void*)(void*)(smem + goff[j] + lane * 16),
                    16, 0, 0);
            }
        }
        __syncthreads();                   // drains vmcnt -> data in LDS
        #pragma unroll
        for (int kk = 0; kk < 2; ++kk){
            bf16x8 bfr[3];
            #pragma unroll
            for (int ni = 0; ni < 3; ++ni){
                int tn = wn + ni * 2;
                bfr[ni] = *(const bf16x8*)(smem + 10240 + ((kk * 6 + tn) * 64 + lane) * 16);
            }
            #pragma unroll
            for (int mi = 0; mi < 3; ++mi){
                if (mi < nTm){
                    int tm = wm + mi * 2;
                    bf16x8 af = *(const bf16x8*)(smem + ((kk * 5 + tm) * 64 + lane) * 16);
                    #pragma unroll
                    for (int ni = 0; ni < 3; ++ni){
                        acc[mi][ni] = __builtin_amdgcn_mfma_f32_16x16x32_bf16(
                            af, bfr[ni], acc[mi][ni], 0, 0, 0);
                    }
                }
            }
        }
    }
    __syncthreads();                       // all frag reads done before overlay

    // C/D layout: col = lane&15 (B-row), row = (lane>>4)*4 + reg (A-row)
    #pragma unroll
    for (int mi = 0; mi < 3; ++mi){
        if (mi < nTm){
            int tm = wm + mi * 2;
            #pragma unroll
            for (int ni = 0; ni < 3; ++ni){
                int tn = wn + ni * 2;
                int col = tn * 16 + frow;
                int rbase = tm * 16 + q * 4;
                if (col < 82){
                    #pragma unroll
                    for (int g = 0; g < 4; ++g){
                        int rowc = rbase + g;
                        if (rowc < 74) Call[rowc * 85 + col] = acc[mi][ni][g];
                    }
                }
            }
        }
    }
    __syncthreads();

    // ----- post-processing: one wave per (b,i) pair, weights in registers -----
    int pb = wave >> 1, pi = wave & 1;
    int bg = b0 + pb, ig = i0 + pi;
    const float* Sv = Call + (pb * 37) * 85 + pi * 41;  // S[r*85+l]; p[r]=S[r*85+40]; qv[l]=S[36*85+l]
    const float* Gb = G + (size_t)bg * 1296;
    const float* Hi = H + (size_t)ig * 1600;
    float w1_txt = w1t[ig];
    float w1_img = w1i[bg];

    // ---- t2i ----
    {   // row norms over words (lanes = regions)
        int r0 = (lane < 36) ? lane : 35;
        float s = 0.f;
        #pragma unroll
        for (int l = 0; l < 40; ++l){ float x = leaky(Sv[r0 * 85 + l]); s = fmaf(x, x, s); }
        if (lane < 36) rnb[wave * 36 + lane] = 1.f / (sqrtf(s) + 1e-8f);
    }
    float t2i_sum;
    {   // lanes = words
        int lc = (lane < 40) ? lane : 39;
        float u[36], dd = 0.f, num = 0.f;
        #pragma unroll
        for (int r = 0; r < 36; ++r){
            float x = leaky(Sv[r * 85 + lc]);
            float e = __expf(9.0f * x * rnb[wave * 36 + r]);
            u[r] = e; dd += e;
            num = fmaf(e, Sv[r * 85 + 40], num);
        }
        float zz = 0.f;
        #pragma unroll
        for (int rr = 0; rr < 36; ++rr){
            float t = 0.f;
            #pragma unroll
            for (int r2 = rr + 1; r2 < 36; ++r2) t = fmaf(Gb[rr * 36 + r2], u[r2], t);
            zz += (2.f * t + Gb[rr * 36 + rr] * u[rr]) * u[rr];
        }
        float w2s = sqrtf(fmaxf(zz, 0.f));
        float sim = (num / dd) / fmaxf(w1_txt * w2s / dd, 1e-8f);
        sim = (lane < 40) ? sim : 0.f;
        #pragma unroll
        for (int off = 32; off > 0; off >>= 1) sim += __shfl_down(sim, off);
        t2i_sum = sim;
    }

    // ---- i2t ----
    {   // column norms over regions (lanes = words)
        int l0 = (lane < 40) ? lane : 39;
        float s = 0.f;
        #pragma unroll
        for (int r = 0; r < 36; ++r){ float x = leaky(Sv[r * 85 + l0]); s = fmaf(x, x, s); }
        if (lane < 40) cnb[wave * 40 + lane] = 1.f / (sqrtf(s) + 1e-8f);
    }
    float i2t_sum;
    {   // lanes = regions
        int rc = (lane < 36) ? lane : 35;
        float v[40], dd = 0.f, num = 0.f;
        #pragma unroll
        for (int l = 0; l < 40; ++l){
            float x = leaky(Sv[rc * 85 + l]);
            float e = __expf(9.0f * x * cnb[wave * 40 + l]);
            v[l] = e; dd += e;
            num = fmaf(e, Sv[36 * 85 + l], num);
        }
        float zz = 0.f;
        #pragma unroll
        for (int ll = 0; ll < 40; ++ll){
            float t = 0.f;
            #pragma unroll
            for (int l2 = ll + 1; l2 < 40; ++l2) t = fmaf(Hi[ll * 40 + l2], v[l2], t);
            zz += (2.f * t + Hi[ll * 40 + ll] * v[ll]) * v[ll];
        }
        float w2s = sqrtf(fmaxf(zz, 0.f));
        float sim = (num / dd) / fmaxf(w1_img * w2s / dd, 1e-8f);
        sim = (lane < 36) ? sim : 0.f;
        #pragma unroll
        for (int off = 32; off > 0; off >>= 1) sim += __shfl_down(sim, off);
        i2t_sum = sim;
    }

    if (lane == 0)
        out[bg * 256 + ig] = t2i_sum * (1.f / 40.f) + i2t_sum * (1.f / 36.f) + Sv[36 * 85 + 40];
}

// ---------------------------------------------------------------------------
extern "C" void kernel_launch(void* const* d_in, const int* in_sizes, int n_in,
                              void* d_out, int out_size, void* d_ws, size_t ws_size,
                              hipStream_t stream){
    const float* pool_img = (const float*)d_in[0];
    const float* img_emb  = (const float*)d_in[1];
    const float* pool_txt = (const float*)d_in[2];
    const float* cap_emb  = (const float*)d_in[3];
    float* out = (float*)d_out;

    char* ws = (char*)d_ws;                         // needs ~43.9 MB
    size_t o = 0;
    u16* imgw = (u16*)(ws + o);  o += (size_t)256 * 37 * 1024 * 2;
    u16* capw = (u16*)(ws + o);  o += (size_t)256 * 41 * 1024 * 2;
    float* G  = (float*)(ws + o); o += (size_t)256 * 36 * 36 * 4;
    float* H  = (float*)(ws + o); o += (size_t)256 * 40 * 40 * 4;
    float* w1i = (float*)(ws + o); o += 1024;
    float* w1t = (float*)(ws + o); o += 1024;

    pack_kernel<<<19968, 256, 0, stream>>>(pool_img, img_emb, pool_txt, cap_emb, imgw, capw);
    norm_kernel<<<512, 256, 0, stream>>>(pool_img, pool_txt, w1i, w1t);
    gram_kernel<<<512, 256, 0, stream>>>(imgw, capw, G, H);
    fused_kernel<<<16384, 256, 0, stream>>>(imgw, capw, G, H, w1i, w1t, out);
}